// Round 12
// baseline (67.807 us; speedup 1.0000x reference)
//
#include <hip/hip_runtime.h>

// TreeLoss: 2-level hierarchical softmax loss.
// z(b)    = 1 + sum_p e^{x_p} * (1 + sum_{c in p} e^{x_c})   (parents p=56..63)
// loss(b) = log z - (x_g + x_parent(g)),  parent(g) = 56 + g/7; out = mean.
//
// R12 = R11 body, single kernel. The final-reduction dispatch (+gap, ~3-5us
// fixed tail) is replaced by per-wave fire-and-forget atomicAdd to out[0]
// (device-scope per guide G12; no return-value dependency, no ACQ_REL -- the
// R4/R9 serialization came from same-line RMW handshakes whose RESULT gated
// block retirement). out[0] is re-zeroed per call by a 4-byte async memset.
// Staging: global_load_lds (16B) HBM->LDS, source-chunk XOR swizzle with the
// matching involution on LDS reads; counted vmcnt waits pipeline 2 tiles/wave;
// no __syncthreads anywhere.

#define THREADS 256               // 4 waves
#define WROWS   32                // rows per tile
#define RPB     256               // rows per block (4 waves x 2 tiles x 32)

__device__ __forceinline__ float elem(const float4& v, int j) {
    return j == 0 ? v.x : j == 1 ? v.y : j == 2 ? v.z : v.w;
}

__device__ __forceinline__ void stage_tile(const float* __restrict__ pred,
                                           int rowBase, float* ldsReg,
                                           int l, int rows) {
    #pragma unroll
    for (int i = 0; i < 8; ++i) {
        const int f   = i * 64 + l;          // LDS chunk slot 0..511
        const int rr  = f >> 4;              // tile row 0..31
        const int sc  = (f & 15) ^ (rr & 7); // pre-swizzled source chunk
        const int row = rowBase + rr;
        if (row < rows) {
            const float* src = pred + (size_t)row * 64 + sc * 4;
            __builtin_amdgcn_global_load_lds(
                (const __attribute__((address_space(1))) float*)src,
                (__attribute__((address_space(3))) float*)(ldsReg + i * 256),
                16, 0, 0);                   // lane l lands at +l*16B = slot f
        }
    }
}

// One row handled by 2 lanes (r = l&31 row, hi = l>>5 parent-half).
__device__ __forceinline__ float compute_half(const float* ldsReg, int g,
                                              int r, int hi) {
    const int x7 = r & 7;
    const float* rowp = ldsReg + r * 64;

    float4 ch[7];
    #pragma unroll
    for (int k = 0; k < 7; ++k) {
        const int c = (7 * hi + k) ^ x7;               // swizzled read
        ch[k] = *(const float4*)(rowp + c * 4);        // ds_read_b128
    }
    const int cp4 = (14 + hi) ^ x7;
    const float4 pv = *(const float4*)(rowp + cp4 * 4);

    float zh = 0.f;
    #pragma unroll
    for (int p = 0; p < 4; ++p) {
        float s = 1.f;
        #pragma unroll
        for (int c = 0; c < 7; ++c) {
            const int idx = p * 7 + c;                 // compile-time
            s += __expf(elem(ch[idx >> 2], idx & 3));
        }
        zh += __expf(elem(pv, p)) * s;
    }
    const float zo = __shfl_xor(zh, 32);               // other parent-half

    const int cg = (g >> 2) ^ x7;
    const float xg = rowp[cg * 4 + (g & 3)];
    const int wp = 56 + g / 7;
    const int cpg = (wp >> 2) ^ x7;
    const float xp = rowp[cpg * 4 + (wp & 3)];

    return __logf(1.f + zh + zo) - xg - xp;
}

__global__ void __launch_bounds__(THREADS) tree_loss(
    const float* __restrict__ pred,   // [rows, 64]
    const int*   __restrict__ gt,     // [rows] 0..55
    float*       __restrict__ out,    // [1], zeroed by async memset each call
    int rows, float inv)
{
    __shared__ float lds[4 * 2 * WROWS * 64];   // 65536 B -> 2 blocks/CU

    const int t  = threadIdx.x;
    const int w  = t >> 6;
    const int l  = t & 63;
    const int r  = l & 31;
    const int hi = l >> 5;

    float* regA = &lds[(w * 2 + 0) * WROWS * 64];
    float* regB = &lds[(w * 2 + 1) * WROWS * 64];

    const int rbA = (int)blockIdx.x * RPB + w * 64;
    const int rbB = rbA + WROWS;
    const int rowA = rbA + r, rowB = rbB + r;

    // gt loads FIRST (oldest in vmcnt queue -> covered by the vmcnt(8) wait).
    const int gA = gt[min(rowA, rows - 1)];
    const int gB = gt[min(rowB, rows - 1)];

    stage_tile(pred, rbA, regA, l, rows);   // 8 DMAs
    stage_tile(pred, rbB, regB, l, rows);   // 8 DMAs

    asm volatile("s_waitcnt vmcnt(8)" ::: "memory");   // gt + tile A complete
    const float lossA = compute_half(regA, gA, r, hi);

    asm volatile("s_waitcnt vmcnt(0)" ::: "memory");   // tile B complete
    const float lossB = compute_half(regB, gB, r, hi);

    float acc = 0.f;
    if (hi == 0 && rowA < rows) acc += lossA;
    if (hi == 0 && rowB < rows) acc += lossB;

    #pragma unroll
    for (int off = 32; off; off >>= 1) acc += __shfl_xor(acc, off);
    if (l == 0) atomicAdd(out, acc * inv);   // fire-and-forget, no dependency
}

extern "C" void kernel_launch(void* const* d_in, const int* in_sizes, int n_in,
                              void* d_out, int out_size, void* d_ws, size_t ws_size,
                              hipStream_t stream) {
    const float* pred = (const float*)d_in[0];   // [B,64] fp32
    const int*   gt   = (const int*)d_in[1];     // [B] int32
    float* out = (float*)d_out;
    const int rows = in_sizes[1];                // BATCH = 262144

    hipMemsetAsync(out, 0, sizeof(float), stream);  // graph-capturable
    const int blocks = (rows + RPB - 1) / RPB;      // 1024
    tree_loss<<<blocks, THREADS, 0, stream>>>(pred, gt, out, rows,
                                              1.0f / (float)rows);
}

// Round 13
// 21.307 us; speedup vs baseline: 3.1824x; 3.1824x over previous
//
#include <hip/hip_runtime.h>

// TreeLoss: 2-level hierarchical softmax loss.
// z(b)    = 1 + sum_p e^{x_p} * (1 + sum_{c in p} e^{x_c})   (parents p=56..63)
// loss(b) = log z - (x_g + x_parent(g)),  parent(g) = 56 + g/7; out = mean.
//
// R13: two kernels (R9/R12: ANY same-address finalization in the heavy kernel
// = +45us of serialized line-RMWs). vs R11: 16-row sub-tiles, 2x4KB buffers
// per wave (32KB/block -> 4 blocks/CU, 16 waves/CU, SINGLE generation for the
// 1024-block grid) and a 2-deep rolling global_load_lds pipeline with counted
// vmcnt. Buffer reuse is ordered by lgkmcnt(0): all ds_reads of a buffer are
// delivered before the overwriting DMA is issued. Source-chunk XOR swizzle
// (line-local) + same involution on reads keeps banks uniform.

#define THREADS 256               // 4 waves
#define SUBROWS 16                // rows per sub-tile
#define RPB     256               // rows per block = 4 waves * 4 subtiles * 16

__device__ __forceinline__ float elem(const float4& v, int j) {
    return j == 0 ? v.x : j == 1 ? v.y : j == 2 ? v.z : v.w;
}

__device__ __forceinline__ void stage_sub(const float* __restrict__ pred,
                                          int rowBase, float* buf,
                                          int l, int rows) {
    #pragma unroll
    for (int i = 0; i < 4; ++i) {
        const int f   = i * 64 + l;          // slot 0..255
        const int rr  = f >> 4;              // sub-tile row 0..15
        const int sc  = (f & 15) ^ (rr & 7); // pre-swizzled source chunk
        const int row = rowBase + rr;
        if (row < rows) {
            const float* src = pred + (size_t)row * 64 + sc * 4;
            __builtin_amdgcn_global_load_lds(
                (const __attribute__((address_space(1))) float*)src,
                (__attribute__((address_space(3))) float*)(buf + i * 256),
                16, 0, 0);                   // lane l -> float offset f*4
        }
    }
}

// Row r (0..15) handled by lanes {r, r+16} (hi = parent-half); lanes 32-63
// duplicate the work (free on SIMD; masked out of the loss).
__device__ __forceinline__ float compute_sub(const float* buf, int g,
                                             int r, int hi) {
    const int x7 = r & 7;
    const float* rowp = buf + r * 64;

    float4 ch[7];
    #pragma unroll
    for (int k = 0; k < 7; ++k) {
        const int c = (7 * hi + k) ^ x7;               // swizzled read
        ch[k] = *(const float4*)(rowp + c * 4);        // ds_read_b128
    }
    const float4 pv = *(const float4*)(rowp + ((14 + hi) ^ x7) * 4);

    float zh = 0.f;
    #pragma unroll
    for (int p = 0; p < 4; ++p) {
        float s = 1.f;
        #pragma unroll
        for (int c = 0; c < 7; ++c) {
            const int idx = p * 7 + c;                 // compile-time
            s += __expf(elem(ch[idx >> 2], idx & 3));
        }
        zh += __expf(elem(pv, p)) * s;
    }
    const float zo = __shfl_xor(zh, 16);               // partner parent-half

    const int cg = (g >> 2) ^ x7;
    const float xg = rowp[cg * 4 + (g & 3)];
    const int wp = 56 + g / 7;
    const int cpg = (wp >> 2) ^ x7;
    const float xp = rowp[cpg * 4 + (wp & 3)];

    return __logf(1.f + zh + zo) - xg - xp;
}

__global__ void __launch_bounds__(THREADS) tree_loss_partial(
    const float* __restrict__ pred,   // [rows, 64]
    const int*   __restrict__ gt,     // [rows] 0..55
    float*       __restrict__ partial,// [gridDim.x * 4]
    int rows)
{
    __shared__ float lds[4 * 2 * SUBROWS * 64];   // 32768 B -> 4 blocks/CU

    const int t  = threadIdx.x;
    const int w  = t >> 6;
    const int l  = t & 63;
    const int r  = l & 15;
    const int hi = (l >> 4) & 1;

    float* buf0 = &lds[w * 2048];
    float* buf1 = buf0 + 1024;

    const int rb  = (int)blockIdx.x * RPB + w * 64;  // wave's 64 rows
    const int rb0 = rb, rb1 = rb + 16, rb2 = rb + 32, rb3 = rb + 48;

    // gt loads FIRST (oldest vmem ops -> retired by the vmcnt(8) wait).
    const int g0 = gt[min(rb0 + r, rows - 1)];
    const int g1 = gt[min(rb1 + r, rows - 1)];
    const int g2 = gt[min(rb2 + r, rows - 1)];
    const int g3 = gt[min(rb3 + r, rows - 1)];

    stage_sub(pred, rb0, buf0, l, rows);             // 4 DMAs
    stage_sub(pred, rb1, buf1, l, rows);             // 4 DMAs  (queue: 4gt+8)

    float acc = 0.f;
    const bool lo = (l < 16);

    asm volatile("s_waitcnt vmcnt(8)" ::: "memory");  // gt + S0 ready
    { float v = compute_sub(buf0, g0, r, hi);
      if (lo && rb0 + r < rows) acc += v; }
    asm volatile("s_waitcnt lgkmcnt(0)" ::: "memory"); // buf0 reads delivered
    stage_sub(pred, rb2, buf0, l, rows);              // overwrite buf0

    asm volatile("s_waitcnt vmcnt(4)" ::: "memory");  // S1 ready
    { float v = compute_sub(buf1, g1, r, hi);
      if (lo && rb1 + r < rows) acc += v; }
    asm volatile("s_waitcnt lgkmcnt(0)" ::: "memory"); // buf1 reads delivered
    stage_sub(pred, rb3, buf1, l, rows);              // overwrite buf1

    asm volatile("s_waitcnt vmcnt(4)" ::: "memory");  // S2 ready
    { float v = compute_sub(buf0, g2, r, hi);
      if (lo && rb2 + r < rows) acc += v; }

    asm volatile("s_waitcnt vmcnt(0)" ::: "memory");  // S3 ready
    { float v = compute_sub(buf1, g3, r, hi);
      if (lo && rb3 + r < rows) acc += v; }

    // Wave reduction (lanes >=16 hold zeros or masked duplicates).
    #pragma unroll
    for (int off = 32; off; off >>= 1) acc += __shfl_xor(acc, off);
    if (l == 0) partial[(size_t)blockIdx.x * 4 + w] = acc;  // no barrier
}

__global__ void __launch_bounds__(1024) tree_loss_final(
    const float* __restrict__ partial, int n,
    float* __restrict__ out, float inv)
{
    float s = 0.0f;
    for (int i = threadIdx.x; i < n; i += 1024) s += partial[i];
    #pragma unroll
    for (int off = 32; off; off >>= 1) s += __shfl_xor(s, off);
    __shared__ float w[16];
    const int lane = threadIdx.x & 63;
    const int wv   = threadIdx.x >> 6;
    if (lane == 0) w[wv] = s;
    __syncthreads();
    if (threadIdx.x == 0) {
        float b = 0.f;
        #pragma unroll
        for (int k = 0; k < 16; ++k) b += w[k];
        out[0] = b * inv;
    }
}

extern "C" void kernel_launch(void* const* d_in, const int* in_sizes, int n_in,
                              void* d_out, int out_size, void* d_ws, size_t ws_size,
                              hipStream_t stream) {
    const float* pred = (const float*)d_in[0];   // [B,64] fp32
    const int*   gt   = (const int*)d_in[1];     // [B] int32
    float* out     = (float*)d_out;
    float* partial = (float*)d_ws;
    const int rows = in_sizes[1];                // BATCH = 262144

    const int blocks = (rows + RPB - 1) / RPB;   // 1024
    tree_loss_partial<<<blocks, THREADS, 0, stream>>>(pred, gt, partial, rows);
    tree_loss_final<<<1, 1024, 0, stream>>>(partial, blocks * 4, out,
                                            1.0f / (float)rows);
}